// Round 9
// baseline (160.435 us; speedup 1.0000x reference)
//
#include <hip/hip_runtime.h>

#define BB 8
#define TT 2048
#define EE 1024
#define HH 128

typedef __bf16 bf16;
typedef __attribute__((ext_vector_type(8))) __bf16 bf16x8;
typedef __attribute__((ext_vector_type(4))) __bf16 bf16x4;
typedef __attribute__((ext_vector_type(4))) float f32x4;
typedef __attribute__((ext_vector_type(16))) float f32x16;

__device__ __host__ inline int qb_off(int qb) {
  int h = qb >> 1;
  return qb + h * (h - 1) + ((qb & 1) ? h : 0);
}
#define NSLAB 72  // qb_off(16); valid (qb,s) pairs per batch

__device__ inline void gload_lds16(const bf16* g, bf16* l) {
  __builtin_amdgcn_global_load_lds((const __attribute__((address_space(1))) unsigned int*)g,
                                   (__attribute__((address_space(3))) unsigned int*)l,
                                   16, 0, 0);
}

// ---- Wt[z*128+n][k] = W_z[k][n], fp32->bf16, LDS transpose ----
__global__ __launch_bounds__(256) void wt_kernel(const float* __restrict__ wq,
                                                 const float* __restrict__ wk,
                                                 const float* __restrict__ wv,
                                                 bf16* __restrict__ wt) {
  __shared__ float tile[64][65];
  const int z = blockIdx.z;
  const float* w = (z == 0) ? wq : ((z == 1) ? wk : wv);
  const int k0 = blockIdx.x * 64;
  const int h0 = blockIdx.y * 64;
  const int c = threadIdx.x & 63;
  const int r0 = threadIdx.x >> 6;
#pragma unroll
  for (int i = 0; i < 16; ++i) {
    int tt = r0 + i * 4;
    tile[tt][c] = w[(size_t)(k0 + tt) * HH + h0 + c];
  }
  __syncthreads();
#pragma unroll
  for (int i = 0; i < 16; ++i) {
    int hh = r0 + i * 4;
    wt[((size_t)(z * HH + h0 + hh)) * EE + k0 + c] = (bf16)tile[c][hh];
  }
}

// ---- gemm v3: reads x fp32 DIRECTLY (xcvt pass eliminated), grid ----
// ---- (128,4) / 2 blocks-CU as in the proven round-5 geometry.     ----
// A: reg-staged fp32->bf16 with in-order-LDS-safe T14 split:
//   ds_read frags -> issue next-A global loads -> MFMA (lgkm covers only
//   the frag reads) -> cvt+ds_write next A -> barrier.
// B (wt bf16, L2-resident): global_load_lds unchanged.
// Same LDS image as before: row tid>>2, 8-elem chunk tid&3.
__global__ __launch_bounds__(256) void gemm_kernel(const float* __restrict__ x,
                                                   const bf16* __restrict__ wt,
                                                   bf16* __restrict__ q,
                                                   bf16* __restrict__ k,
                                                   bf16* __restrict__ vt) {
  __shared__ bf16 As[2][128 * 32];  // 16 KB
  __shared__ bf16 Bs[2][96 * 32];   // 12 KB
  const int tid = threadIdx.x;
  const int lane = tid & 63;
  const int wave = tid >> 6;
  const int l16 = lane & 15;
  const int quad = lane >> 4;
  const int wm = wave & 1;   // M half (64 rows)
  const int wn = wave >> 1;  // N half (48 cols)
  const int bm = blockIdx.x;
  const int ntile = blockIdx.y;

  const int trow = tid >> 2;        // 0..63
  const int tsub = (tid & 3) * 8;   // 0,8,16,24
  const float* gA = x + (size_t)(bm * 128 + trow) * EE + tsub;
  const bf16* gB = wt + (size_t)(ntile * 96 + trow) * EE + tsub;
  const int awr = trow * 32 + tsub;  // LDS write offset (elements)

  f32x4 acc[4][3];
#pragma unroll
  for (int rg = 0; rg < 4; ++rg)
#pragma unroll
    for (int nt = 0; nt < 3; ++nt) acc[rg][nt] = f32x4{0.f, 0.f, 0.f, 0.f};

  auto stageB = [&](int bufi, int ks) {
    gload_lds16(gB + ks * 32, &Bs[bufi][wave * 512]);
    if (tid < 128)
      gload_lds16(gB + (size_t)64 * EE + ks * 32, &Bs[bufi][2048 + wave * 512]);
  };
  auto packA = [](f32x4 a0, f32x4 a1) {
    bf16x8 ab;
#pragma unroll
    for (int jj = 0; jj < 4; ++jj) { ab[jj] = (bf16)a0[jj]; ab[jj + 4] = (bf16)a1[jj]; }
    return ab;
  };

  {  // prologue: stage buf0
    f32x4 a0 = *(const f32x4*)(gA);
    f32x4 a1 = *(const f32x4*)(gA + 4);
    f32x4 a2 = *(const f32x4*)(gA + (size_t)64 * EE);
    f32x4 a3 = *(const f32x4*)(gA + (size_t)64 * EE + 4);
    stageB(0, 0);
    *(bf16x8*)&As[0][awr] = packA(a0, a1);
    *(bf16x8*)&As[0][2048 + awr] = packA(a2, a3);
  }
  __syncthreads();

  int buf = 0;
  for (int ks = 0; ks < EE / 32; ++ks) {
    // 1) frag ds_reads issue FIRST (in-order LDS queue: MFMA's lgkm wait
    //    then does not cover the later A ds_writes)
    bf16x8 af[4], bf_[3];
#pragma unroll
    for (int rg = 0; rg < 4; ++rg)
      af[rg] = *(const bf16x8*)&As[buf][(wm * 64 + rg * 16 + l16) * 32 + quad * 8];
#pragma unroll
    for (int nt = 0; nt < 3; ++nt)
      bf_[nt] = *(const bf16x8*)&Bs[buf][(wn * 48 + nt * 16 + l16) * 32 + quad * 8];

    // 2) issue next-tile loads (latency hides under MFMA)
    f32x4 a0, a1, a2, a3;
    if (ks < EE / 32 - 1) {
      const float* gn = gA + (ks + 1) * 32;
      a0 = *(const f32x4*)(gn);
      a1 = *(const f32x4*)(gn + 4);
      a2 = *(const f32x4*)(gn + (size_t)64 * EE);
      a3 = *(const f32x4*)(gn + (size_t)64 * EE + 4);
      stageB(buf ^ 1, ks + 1);
    }

    // 3) MFMA
#pragma unroll
    for (int rg = 0; rg < 4; ++rg)
#pragma unroll
      for (int nt = 0; nt < 3; ++nt)
        acc[rg][nt] = __builtin_amdgcn_mfma_f32_16x16x32_bf16(af[rg], bf_[nt], acc[rg][nt], 0, 0, 0);

    // 4) cvt + ds_write next A (after MFMA; drained by the barrier)
    if (ks < EE / 32 - 1) {
      *(bf16x8*)&As[buf ^ 1][awr] = packA(a0, a1);
      *(bf16x8*)&As[buf ^ 1][2048 + awr] = packA(a2, a3);
    }
    __syncthreads();  // drains vmcnt+lgkmcnt after compute
    buf ^= 1;
  }

#pragma unroll
  for (int rg = 0; rg < 4; ++rg)
#pragma unroll
    for (int nt = 0; nt < 3; ++nt) {
      int col = ntile * 96 + wn * 48 + nt * 16 + l16;
      int z = col >> 7;          // wave-uniform (col base 16-aligned)
      int n = col & 127;
      int row0 = bm * 128 + wm * 64 + rg * 16 + quad * 4;
      if (z == 2) {
        // V: write transposed. 4 consecutive t at fixed h -> 8B store.
        int bb = row0 >> 11;
        int t0 = row0 & (TT - 1);
        bf16x4 pkv;
#pragma unroll
        for (int r = 0; r < 4; ++r) pkv[r] = (bf16)acc[rg][nt][r];
        *(bf16x4*)&vt[((size_t)(bb * HH + n)) * TT + t0] = pkv;
      } else {
        bf16* op = (z == 0) ? q : k;
#pragma unroll
        for (int r = 0; r < 4; ++r)
          op[(size_t)(row0 + r) * HH + n] = (bf16)acc[rg][nt][r];
      }
    }
}

// ---- flash v7: K double-buffered LDS, V single-buffered (48 KB), ----
// ---- in-register softmax (T12). (unchanged, banked config)       ----
__device__ __forceinline__ unsigned pk2(float a, float b) {
  union { __bf16 h[2]; unsigned u; } x;
  x.h[0] = (__bf16)a;
  x.h[1] = (__bf16)b;
  return x.u;
}

// v_permlane32_swap_b32: vdst.hi(lanes 32-63) <-> vsrc.lo(lanes 0-31)
__device__ __forceinline__ void plswap(unsigned& a, unsigned& b) {
  asm volatile("v_permlane32_swap_b32 %0, %1" : "+v"(a), "+v"(b));
}

__global__ __launch_bounds__(256, 2) void flash_kernel(const bf16* __restrict__ q,
                                                       const bf16* __restrict__ k,
                                                       const bf16* __restrict__ vt,
                                                       bf16* __restrict__ opart,
                                                       float* __restrict__ lpart) {
  __shared__ bf16 Ks[2][64 * 128];  // 32 KB, byte^=((r&7)<<4) swizzle
  __shared__ bf16 Vs[128 * 64];     // 16 KB single buffer, same swizzle

  const int b = blockIdx.x & 7;
  int j = (NSLAB - 1) - (blockIdx.x >> 3);  // heavy (high-qb) blocks first
  int qb = 0, ns = 1;
  while (j >= ns) { j -= ns; ++qb; ns = ((2 * qb + 1) >> 2) + 1; }
  const int s = j;
  const int kt0 = s * 4;
  const int kt1 = min(kt0 + 3, 2 * qb + 1);

  const int tid = threadIdx.x;
  const int lane = tid & 63;
  const int wave = tid >> 6;
  const int l32 = lane & 31;
  const int hi = lane >> 5;
  const int qrow = qb * 128 + wave * 32 + l32;
  const int kdiag = qb * 4 + wave;  // diagonal 32-block for this wave

  // Q fragments: lane holds q-row = l&31 (B-operand of swapped QK^T)
  bf16x8 qf[8];
  {
    const bf16* qp = q + (size_t)(b * TT + qrow) * HH + hi * 8;
#pragma unroll
    for (int h16 = 0; h16 < 8; ++h16) qf[h16] = *(const bf16x8*)(qp + h16 * 16);
  }

  f32x16 O[4];
#pragma unroll
  for (int ht = 0; ht < 4; ++ht)
#pragma unroll
    for (int r = 0; r < 16; ++r) O[ht][r] = 0.f;
  float L = 0.f;

  // staging source mapping (pre-swizzled so linear LDS + swizzled read match)
  const int krow_s = tid >> 4;                    // K: row within 16-row round
  const int kchk_s = (tid & 15) ^ (krow_s & 7);   // 16B chunk, inverse-swizzled
  const int vrow_s = tid >> 3;                    // V: row within 32-row round
  const int vchk_s = (tid & 7) ^ (vrow_s & 7);
  const bf16* kg = k + (size_t)b * TT * HH;
  const bf16* vg = vt + (size_t)b * HH * TT;

  auto stageK = [&](int bufi, int kt) {
#pragma unroll
    for (int i = 0; i < 4; ++i)
      gload_lds16(kg + (size_t)(kt * 64 + i * 16 + krow_s) * HH + kchk_s * 8,
                  &Ks[bufi][(i * 256 + wave * 64) * 8]);
  };
  auto stageV = [&](int kt) {
#pragma unroll
    for (int i = 0; i < 4; ++i)
      gload_lds16(vg + (size_t)(i * 32 + vrow_s) * TT + kt * 64 + vchk_s * 8,
                  &Vs[(i * 256 + wave * 64) * 8]);
  };

  const int kxor = (l32 & 7) << 3;        // read-side XOR, element units
  const float c_ = 0.12753257680406733f;  // log2(e)/sqrt(128)

  stageK(0, kt0);
  stageV(kt0);
  __syncthreads();  // prologue drain: K0 + V0 staged

  int buf = 0;
  for (int kt = kt0; kt <= kt1; ++kt) {
    if (kt < kt1) stageK(buf ^ 1, kt + 1);  // K prefetch overlaps compute

#pragma unroll
    for (int khalf = 0; khalf < 2; ++khalf) {
      const int k32 = kt * 2 + khalf;
      if (k32 <= kdiag) {
        // K fragments from LDS (swizzled read)
        const bf16* kls = &Ks[buf][(khalf * 32 + l32) * 128];
        bf16x8 kf[8];
#pragma unroll
        for (int h16 = 0; h16 < 8; ++h16)
          kf[h16] = *(const bf16x8*)&kls[(h16 * 16 + hi * 8) ^ kxor];

        // S^T[k][q] = K . Q^T  (lane: q=l&31; regs: k=(r&3)+8*(r>>2)+4*hi)
        f32x16 S;
#pragma unroll
        for (int r = 0; r < 16; ++r) S[r] = 0.f;
        __builtin_amdgcn_s_setprio(1);
#pragma unroll
        for (int h16 = 0; h16 < 8; ++h16)
          S = __builtin_amdgcn_mfma_f32_32x32x16_bf16(kf[h16], qf[h16], S, 0, 0, 0);
        __builtin_amdgcn_s_setprio(0);

        // softmax (no-max; scale folded into exp2), in registers
        float p[16];
        if (k32 == kdiag) {
          const int kkb = k32 * 32 + 4 * hi;
#pragma unroll
          for (int r = 0; r < 16; ++r) {
            int kk = kkb + (r & 3) + 8 * (r >> 2);
            p[r] = (kk <= qrow) ? exp2f(S[r] * c_) : 0.f;
          }
        } else {
#pragma unroll
          for (int r = 0; r < 16; ++r) p[r] = exp2f(S[r] * c_);
        }
        // 4-deep tree sum (breaks 16-deep dependent add chain)
        L += (((p[0] + p[1]) + (p[2] + p[3])) + ((p[4] + p[5]) + (p[6] + p[7]))) +
             (((p[8] + p[9]) + (p[10] + p[11])) + ((p[12] + p[13]) + (p[14] + p[15])));

        // P -> bf16 A-frag (pack + permlane32_swap, T12), then PV from LDS V
#pragma unroll
        for (int s16 = 0; s16 < 2; ++s16) {
          unsigned w0 = pk2(p[s16 * 8 + 0], p[s16 * 8 + 1]);
          unsigned w1 = pk2(p[s16 * 8 + 2], p[s16 * 8 + 3]);
          unsigned w2 = pk2(p[s16 * 8 + 4], p[s16 * 8 + 5]);
          unsigned w3 = pk2(p[s16 * 8 + 6], p[s16 * 8 + 7]);
          plswap(w0, w2);
          plswap(w1, w3);
          union { unsigned u[4]; bf16x8 v; } af;
          af.u[0] = w0;
          af.u[1] = w1;
          af.u[2] = w2;
          af.u[3] = w3;
          bf16x8 vf[4];
#pragma unroll
          for (int ht = 0; ht < 4; ++ht)
            vf[ht] = *(const bf16x8*)&Vs[(l32 + 32 * ht) * 64 +
                                         ((khalf * 32 + s16 * 16 + hi * 8) ^ kxor)];
          __builtin_amdgcn_s_setprio(1);
#pragma unroll
          for (int ht = 0; ht < 4; ++ht)
            O[ht] = __builtin_amdgcn_mfma_f32_32x32x16_bf16(af.v, vf[ht], O[ht], 0, 0, 0);
          __builtin_amdgcn_s_setprio(0);
        }
      }
    }
    __syncthreads();  // all waves done reading Vs + Ks[buf]; K(kt+1) drained
    if (kt < kt1) {
      stageV(kt + 1);   // safe: everyone past the read of Vs(kt)
      __syncthreads();  // V(kt+1) visible before next compute
    }
    buf ^= 1;
  }

  L += __shfl_xor(L, 32, 64);  // partner half holds complementary k-subset

  const size_t slab = (size_t)(b * NSLAB + qb_off(qb) + s);
  bf16* op = opart + slab * (128 * 128) + (size_t)wave * 32 * 128;
#pragma unroll
  for (int ht = 0; ht < 4; ++ht)
#pragma unroll
    for (int r = 0; r < 16; ++r) {
      int qr = (r & 3) + 8 * (r >> 2) + 4 * hi;
      op[qr * 128 + ht * 32 + l32] = (bf16)O[ht][r];
    }
  if (hi == 0) lpart[slab * 128 + wave * 32 + l32] = L;
}

// ---- combine: grid (b, qt16, half) -> 2048 blocks of 128 thr ----
__global__ __launch_bounds__(128) void combine_kernel(const bf16* __restrict__ opart,
                                                      const float* __restrict__ lpart,
                                                      float* __restrict__ out) {
  const int b = blockIdx.x;
  const int qt16 = blockIdx.y;
  const int half = blockIdx.z;
  const int row = threadIdx.x >> 3;
  const int colo = (threadIdx.x & 7) * 8 + half * 64;
  const int qb = qt16 >> 3;
  const int srow = (qt16 & 7) * 16 + row;
  const int ns = ((2 * qb + 1) >> 2) + 1;  // 1..8
  const size_t slab0 = (size_t)(b * NSLAB + qb_off(qb));

  float acc[8];
#pragma unroll
  for (int j = 0; j < 8; ++j) acc[j] = 0.f;
  float L = 0.f;

  int s = 0;
  for (; s + 4 <= ns; s += 4) {
    float l0 = lpart[(slab0 + s + 0) * 128 + srow];
    float l1 = lpart[(slab0 + s + 1) * 128 + srow];
    float l2 = lpart[(slab0 + s + 2) * 128 + srow];
    float l3 = lpart[(slab0 + s + 3) * 128 + srow];
    bf16x8 v0 = *(const bf16x8*)(opart + (slab0 + s + 0) * (128 * 128) + srow * 128 + colo);
    bf16x8 v1 = *(const bf16x8*)(opart + (slab0 + s + 1) * (128 * 128) + srow * 128 + colo);
    bf16x8 v2 = *(const bf16x8*)(opart + (slab0 + s + 2) * (128 * 128) + srow * 128 + colo);
    bf16x8 v3 = *(const bf16x8*)(opart + (slab0 + s + 3) * (128 * 128) + srow * 128 + colo);
    L += (l0 + l1) + (l2 + l3);
#pragma unroll
    for (int j = 0; j < 8; ++j)
      acc[j] += ((float)v0[j] + (float)v1[j]) + ((float)v2[j] + (float)v3[j]);
  }
  for (; s < ns; ++s) {
    L += lpart[(slab0 + s) * 128 + srow];
    bf16x8 ov = *(const bf16x8*)(opart + (slab0 + s) * (128 * 128) + srow * 128 + colo);
#pragma unroll
    for (int j = 0; j < 8; ++j) acc[j] += (float)ov[j];
  }
  float invL = 1.f / L;
  float* o = out + ((size_t)(b * TT + qt16 * 16 + row)) * HH + colo;
  f32x4 o0, o1;
#pragma unroll
  for (int j = 0; j < 4; ++j) { o0[j] = acc[j] * invL; o1[j] = acc[j + 4] * invL; }
  *(f32x4*)o = o0;
  *(f32x4*)(o + 4) = o1;
}

extern "C" void kernel_launch(void* const* d_in, const int* in_sizes, int n_in,
                              void* d_out, int out_size, void* d_ws, size_t ws_size,
                              hipStream_t stream) {
  const float* x = (const float*)d_in[0];
  const float* wq = (const float*)d_in[1];
  const float* wk = (const float*)d_in[2];
  const float* wv = (const float*)d_in[3];
  float* out = (float*)d_out;

  char* ws = (char*)d_ws;
  const size_t NE = (size_t)BB * TT * HH;  // 2,097,152
  bf16* wt = (bf16*)ws;                    // 768 KB
  bf16* q = (bf16*)(ws + (1 << 20));       // 4 MiB each
  bf16* k = q + NE;
  bf16* vt = k + NE;                       // V written pre-transposed by gemm
  bf16* opart = (bf16*)(ws + (16 << 20));  // 18.9 MiB
  float* lpart = (float*)(opart + (size_t)(BB * NSLAB) * 128 * 128);
  // total ws use: ~36 MiB

  wt_kernel<<<dim3(16, 2, 3), 256, 0, stream>>>(wq, wk, wv, wt);
  gemm_kernel<<<dim3(128, 4), 256, 0, stream>>>(x, wt, q, k, vt);
  flash_kernel<<<dim3(576), 256, 0, stream>>>(q, k, vt, opart, lpart);
  combine_kernel<<<dim3(8, 128, 2), 128, 0, stream>>>(opart, lpart, out);
}

// Round 10
// 157.055 us; speedup vs baseline: 1.0215x; 1.0215x over previous
//
#include <hip/hip_runtime.h>

#define BB 8
#define TT 2048
#define EE 1024
#define HH 128

typedef __bf16 bf16;
typedef __attribute__((ext_vector_type(8))) __bf16 bf16x8;
typedef __attribute__((ext_vector_type(4))) __bf16 bf16x4;
typedef __attribute__((ext_vector_type(4))) float f32x4;
typedef __attribute__((ext_vector_type(16))) float f32x16;

__device__ __host__ inline int qb_off(int qb) {
  int h = qb >> 1;
  return qb + h * (h - 1) + ((qb & 1) ? h : 0);
}
#define NSLAB 72  // qb_off(16); valid (qb,s) pairs per batch

__device__ inline void gload_lds16(const bf16* g, bf16* l) {
  __builtin_amdgcn_global_load_lds((const __attribute__((address_space(1))) unsigned int*)g,
                                   (__attribute__((address_space(3))) unsigned int*)l,
                                   16, 0, 0);
}

// ---- Wt[z*128+n][k] = W_z[k][n], fp32->bf16, LDS transpose ----
__global__ __launch_bounds__(256) void wt_kernel(const float* __restrict__ wq,
                                                 const float* __restrict__ wk,
                                                 const float* __restrict__ wv,
                                                 bf16* __restrict__ wt) {
  __shared__ float tile[64][65];
  const int z = blockIdx.z;
  const float* w = (z == 0) ? wq : ((z == 1) ? wk : wv);
  const int k0 = blockIdx.x * 64;
  const int h0 = blockIdx.y * 64;
  const int c = threadIdx.x & 63;
  const int r0 = threadIdx.x >> 6;
#pragma unroll
  for (int i = 0; i < 16; ++i) {
    int tt = r0 + i * 4;
    tile[tt][c] = w[(size_t)(k0 + tt) * HH + h0 + c];
  }
  __syncthreads();
#pragma unroll
  for (int i = 0; i < 16; ++i) {
    int hh = r0 + i * 4;
    wt[((size_t)(z * HH + h0 + hh)) * EE + k0 + c] = (bf16)tile[c][hh];
  }
}

// ---- gemm v3b: x fp32 read directly; A reg-staged at PIPELINE DEPTH 2 ----
// iter ks: {frag ds_reads -> issue A(ks+2)+B(ks+1) -> MFMA -> cvt+write
// A(ks+1) from regs loaded LAST iter -> barrier}. The vmcnt wait before
// the cvt now covers a full iteration (~400-600cy), not ~60cy (round-9
// failure). As padded to 40 elem/row (20 banks): 8-way write conflict
// -> 2-way (free). B linear (global_load_lds).
__global__ __launch_bounds__(256) void gemm_kernel(const float* __restrict__ x,
                                                   const bf16* __restrict__ wt,
                                                   bf16* __restrict__ q,
                                                   bf16* __restrict__ k,
                                                   bf16* __restrict__ vt) {
  __shared__ bf16 As[2][128 * 40];  // 10 KB x2 (padded)
  __shared__ bf16 Bs[2][96 * 32];   // 6 KB x2
  const int tid = threadIdx.x;
  const int lane = tid & 63;
  const int wave = tid >> 6;
  const int l16 = lane & 15;
  const int quad = lane >> 4;
  const int wm = wave & 1;   // M half (64 rows)
  const int wn = wave >> 1;  // N half (48 cols)
  const int bm = blockIdx.x;
  const int ntile = blockIdx.y;

  const int trow = tid >> 2;        // 0..63
  const int tsub = (tid & 3) * 8;   // 0,8,16,24
  const float* gA = x + (size_t)(bm * 128 + trow) * EE + tsub;
  const bf16* gB = wt + (size_t)(ntile * 96 + trow) * EE + tsub;
  const int awr = trow * 40 + tsub;  // padded LDS write offset (elements)

  f32x4 acc[4][3];
#pragma unroll
  for (int rg = 0; rg < 4; ++rg)
#pragma unroll
    for (int nt = 0; nt < 3; ++nt) acc[rg][nt] = f32x4{0.f, 0.f, 0.f, 0.f};

  auto stageB = [&](int bufi, int ks) {
    gload_lds16(gB + ks * 32, &Bs[bufi][wave * 512]);
    if (tid < 128)
      gload_lds16(gB + (size_t)64 * EE + ks * 32, &Bs[bufi][2048 + wave * 512]);
  };
  auto loadA = [&](int ks, f32x4* r) {
    const float* gn = gA + ks * 32;
    r[0] = *(const f32x4*)(gn);
    r[1] = *(const f32x4*)(gn + 4);
    r[2] = *(const f32x4*)(gn + (size_t)64 * EE);
    r[3] = *(const f32x4*)(gn + (size_t)64 * EE + 4);
  };
  auto writeA = [&](int bufi, const f32x4* r) {
    bf16x8 ab0, ab1;
#pragma unroll
    for (int jj = 0; jj < 4; ++jj) {
      ab0[jj] = (bf16)r[0][jj]; ab0[jj + 4] = (bf16)r[1][jj];
      ab1[jj] = (bf16)r[2][jj]; ab1[jj + 4] = (bf16)r[3][jj];
    }
    *(bf16x8*)&As[bufi][awr] = ab0;
    *(bf16x8*)&As[bufi][64 * 40 + awr] = ab1;
  };

  f32x4 rA0[4], rA1[4];
  {  // prologue: A(0)->As[0]; issue A(1)->rA1; B(0) staged
    loadA(0, rA0);
    stageB(0, 0);
    writeA(0, rA0);
    loadA(1, rA1);
  }
  __syncthreads();

  auto body = [&](int ks, int buf, f32x4* rIssue, f32x4* rWrite) {
    // 1) frag ds_reads FIRST (MFMA's lgkm wait covers only these)
    bf16x8 af[4], bf_[3];
#pragma unroll
    for (int rg = 0; rg < 4; ++rg)
      af[rg] = *(const bf16x8*)&As[buf][(wm * 64 + rg * 16 + l16) * 40 + quad * 8];
#pragma unroll
    for (int nt = 0; nt < 3; ++nt)
      bf_[nt] = *(const bf16x8*)&Bs[buf][(wn * 48 + nt * 16 + l16) * 32 + quad * 8];

    // 2) issue loads: A two tiles ahead, B one tile ahead
    if (ks + 2 < EE / 32) loadA(ks + 2, rIssue);
    if (ks + 1 < EE / 32) stageB(buf ^ 1, ks + 1);

    // 3) MFMA
#pragma unroll
    for (int rg = 0; rg < 4; ++rg)
#pragma unroll
      for (int nt = 0; nt < 3; ++nt)
        acc[rg][nt] = __builtin_amdgcn_mfma_f32_16x16x32_bf16(af[rg], bf_[nt], acc[rg][nt], 0, 0, 0);

    // 4) cvt + ds_write A(ks+1) from regs loaded LAST iteration
    if (ks + 1 < EE / 32) writeA(buf ^ 1, rWrite);
    __syncthreads();
  };

  for (int ks = 0; ks < EE / 32; ks += 2) {  // unroll-2: static reg-set indexing
    body(ks, 0, rA0, rA1);      // issue A(ks+2)->rA0, write A(ks+1)<-rA1
    body(ks + 1, 1, rA1, rA0);  // issue A(ks+3)->rA1, write A(ks+2)<-rA0
  }

#pragma unroll
  for (int rg = 0; rg < 4; ++rg)
#pragma unroll
    for (int nt = 0; nt < 3; ++nt) {
      int col = ntile * 96 + wn * 48 + nt * 16 + l16;
      int z = col >> 7;          // wave-uniform (col base 16-aligned)
      int n = col & 127;
      int row0 = bm * 128 + wm * 64 + rg * 16 + quad * 4;
      if (z == 2) {
        // V: write transposed. 4 consecutive t at fixed h -> 8B store.
        int bb = row0 >> 11;
        int t0 = row0 & (TT - 1);
        bf16x4 pkv;
#pragma unroll
        for (int r = 0; r < 4; ++r) pkv[r] = (bf16)acc[rg][nt][r];
        *(bf16x4*)&vt[((size_t)(bb * HH + n)) * TT + t0] = pkv;
      } else {
        bf16* op = (z == 0) ? q : k;
#pragma unroll
        for (int r = 0; r < 4; ++r)
          op[(size_t)(row0 + r) * HH + n] = (bf16)acc[rg][nt][r];
      }
    }
}

// ---- flash v7: K double-buffered LDS, V single-buffered (48 KB), ----
// ---- in-register softmax (T12). (unchanged, banked config)       ----
__device__ __forceinline__ unsigned pk2(float a, float b) {
  union { __bf16 h[2]; unsigned u; } x;
  x.h[0] = (__bf16)a;
  x.h[1] = (__bf16)b;
  return x.u;
}

// v_permlane32_swap_b32: vdst.hi(lanes 32-63) <-> vsrc.lo(lanes 0-31)
__device__ __forceinline__ void plswap(unsigned& a, unsigned& b) {
  asm volatile("v_permlane32_swap_b32 %0, %1" : "+v"(a), "+v"(b));
}

__global__ __launch_bounds__(256, 2) void flash_kernel(const bf16* __restrict__ q,
                                                       const bf16* __restrict__ k,
                                                       const bf16* __restrict__ vt,
                                                       bf16* __restrict__ opart,
                                                       float* __restrict__ lpart) {
  __shared__ bf16 Ks[2][64 * 128];  // 32 KB, byte^=((r&7)<<4) swizzle
  __shared__ bf16 Vs[128 * 64];     // 16 KB single buffer, same swizzle

  const int b = blockIdx.x & 7;
  int j = (NSLAB - 1) - (blockIdx.x >> 3);  // heavy (high-qb) blocks first
  int qb = 0, ns = 1;
  while (j >= ns) { j -= ns; ++qb; ns = ((2 * qb + 1) >> 2) + 1; }
  const int s = j;
  const int kt0 = s * 4;
  const int kt1 = min(kt0 + 3, 2 * qb + 1);

  const int tid = threadIdx.x;
  const int lane = tid & 63;
  const int wave = tid >> 6;
  const int l32 = lane & 31;
  const int hi = lane >> 5;
  const int qrow = qb * 128 + wave * 32 + l32;
  const int kdiag = qb * 4 + wave;  // diagonal 32-block for this wave

  // Q fragments: lane holds q-row = l&31 (B-operand of swapped QK^T)
  bf16x8 qf[8];
  {
    const bf16* qp = q + (size_t)(b * TT + qrow) * HH + hi * 8;
#pragma unroll
    for (int h16 = 0; h16 < 8; ++h16) qf[h16] = *(const bf16x8*)(qp + h16 * 16);
  }

  f32x16 O[4];
#pragma unroll
  for (int ht = 0; ht < 4; ++ht)
#pragma unroll
    for (int r = 0; r < 16; ++r) O[ht][r] = 0.f;
  float L = 0.f;

  // staging source mapping (pre-swizzled so linear LDS + swizzled read match)
  const int krow_s = tid >> 4;                    // K: row within 16-row round
  const int kchk_s = (tid & 15) ^ (krow_s & 7);   // 16B chunk, inverse-swizzled
  const int vrow_s = tid >> 3;                    // V: row within 32-row round
  const int vchk_s = (tid & 7) ^ (vrow_s & 7);
  const bf16* kg = k + (size_t)b * TT * HH;
  const bf16* vg = vt + (size_t)b * HH * TT;

  auto stageK = [&](int bufi, int kt) {
#pragma unroll
    for (int i = 0; i < 4; ++i)
      gload_lds16(kg + (size_t)(kt * 64 + i * 16 + krow_s) * HH + kchk_s * 8,
                  &Ks[bufi][(i * 256 + wave * 64) * 8]);
  };
  auto stageV = [&](int kt) {
#pragma unroll
    for (int i = 0; i < 4; ++i)
      gload_lds16(vg + (size_t)(i * 32 + vrow_s) * TT + kt * 64 + vchk_s * 8,
                  &Vs[(i * 256 + wave * 64) * 8]);
  };

  const int kxor = (l32 & 7) << 3;        // read-side XOR, element units
  const float c_ = 0.12753257680406733f;  // log2(e)/sqrt(128)

  stageK(0, kt0);
  stageV(kt0);
  __syncthreads();  // prologue drain: K0 + V0 staged

  int buf = 0;
  for (int kt = kt0; kt <= kt1; ++kt) {
    if (kt < kt1) stageK(buf ^ 1, kt + 1);  // K prefetch overlaps compute

#pragma unroll
    for (int khalf = 0; khalf < 2; ++khalf) {
      const int k32 = kt * 2 + khalf;
      if (k32 <= kdiag) {
        // K fragments from LDS (swizzled read)
        const bf16* kls = &Ks[buf][(khalf * 32 + l32) * 128];
        bf16x8 kf[8];
#pragma unroll
        for (int h16 = 0; h16 < 8; ++h16)
          kf[h16] = *(const bf16x8*)&kls[(h16 * 16 + hi * 8) ^ kxor];

        // S^T[k][q] = K . Q^T  (lane: q=l&31; regs: k=(r&3)+8*(r>>2)+4*hi)
        f32x16 S;
#pragma unroll
        for (int r = 0; r < 16; ++r) S[r] = 0.f;
        __builtin_amdgcn_s_setprio(1);
#pragma unroll
        for (int h16 = 0; h16 < 8; ++h16)
          S = __builtin_amdgcn_mfma_f32_32x32x16_bf16(kf[h16], qf[h16], S, 0, 0, 0);
        __builtin_amdgcn_s_setprio(0);

        // softmax (no-max; scale folded into exp2), in registers
        float p[16];
        if (k32 == kdiag) {
          const int kkb = k32 * 32 + 4 * hi;
#pragma unroll
          for (int r = 0; r < 16; ++r) {
            int kk = kkb + (r & 3) + 8 * (r >> 2);
            p[r] = (kk <= qrow) ? exp2f(S[r] * c_) : 0.f;
          }
        } else {
#pragma unroll
          for (int r = 0; r < 16; ++r) p[r] = exp2f(S[r] * c_);
        }
        // 4-deep tree sum (breaks 16-deep dependent add chain)
        L += (((p[0] + p[1]) + (p[2] + p[3])) + ((p[4] + p[5]) + (p[6] + p[7]))) +
             (((p[8] + p[9]) + (p[10] + p[11])) + ((p[12] + p[13]) + (p[14] + p[15])));

        // P -> bf16 A-frag (pack + permlane32_swap, T12), then PV from LDS V
#pragma unroll
        for (int s16 = 0; s16 < 2; ++s16) {
          unsigned w0 = pk2(p[s16 * 8 + 0], p[s16 * 8 + 1]);
          unsigned w1 = pk2(p[s16 * 8 + 2], p[s16 * 8 + 3]);
          unsigned w2 = pk2(p[s16 * 8 + 4], p[s16 * 8 + 5]);
          unsigned w3 = pk2(p[s16 * 8 + 6], p[s16 * 8 + 7]);
          plswap(w0, w2);
          plswap(w1, w3);
          union { unsigned u[4]; bf16x8 v; } af;
          af.u[0] = w0;
          af.u[1] = w1;
          af.u[2] = w2;
          af.u[3] = w3;
          bf16x8 vf[4];
#pragma unroll
          for (int ht = 0; ht < 4; ++ht)
            vf[ht] = *(const bf16x8*)&Vs[(l32 + 32 * ht) * 64 +
                                         ((khalf * 32 + s16 * 16 + hi * 8) ^ kxor)];
          __builtin_amdgcn_s_setprio(1);
#pragma unroll
          for (int ht = 0; ht < 4; ++ht)
            O[ht] = __builtin_amdgcn_mfma_f32_32x32x16_bf16(af.v, vf[ht], O[ht], 0, 0, 0);
          __builtin_amdgcn_s_setprio(0);
        }
      }
    }
    __syncthreads();  // all waves done reading Vs + Ks[buf]; K(kt+1) drained
    if (kt < kt1) {
      stageV(kt + 1);   // safe: everyone past the read of Vs(kt)
      __syncthreads();  // V(kt+1) visible before next compute
    }
    buf ^= 1;
  }

  L += __shfl_xor(L, 32, 64);  // partner half holds complementary k-subset

  const size_t slab = (size_t)(b * NSLAB + qb_off(qb) + s);
  bf16* op = opart + slab * (128 * 128) + (size_t)wave * 32 * 128;
#pragma unroll
  for (int ht = 0; ht < 4; ++ht)
#pragma unroll
    for (int r = 0; r < 16; ++r) {
      int qr = (r & 3) + 8 * (r >> 2) + 4 * hi;
      op[qr * 128 + ht * 32 + l32] = (bf16)O[ht][r];
    }
  if (hi == 0) lpart[slab * 128 + wave * 32 + l32] = L;
}

// ---- combine: grid (b, qt16, half) -> 2048 blocks of 128 thr ----
__global__ __launch_bounds__(128) void combine_kernel(const bf16* __restrict__ opart,
                                                      const float* __restrict__ lpart,
                                                      float* __restrict__ out) {
  const int b = blockIdx.x;
  const int qt16 = blockIdx.y;
  const int half = blockIdx.z;
  const int row = threadIdx.x >> 3;
  const int colo = (threadIdx.x & 7) * 8 + half * 64;
  const int qb = qt16 >> 3;
  const int srow = (qt16 & 7) * 16 + row;
  const int ns = ((2 * qb + 1) >> 2) + 1;  // 1..8
  const size_t slab0 = (size_t)(b * NSLAB + qb_off(qb));

  float acc[8];
#pragma unroll
  for (int j = 0; j < 8; ++j) acc[j] = 0.f;
  float L = 0.f;

  int s = 0;
  for (; s + 4 <= ns; s += 4) {
    float l0 = lpart[(slab0 + s + 0) * 128 + srow];
    float l1 = lpart[(slab0 + s + 1) * 128 + srow];
    float l2 = lpart[(slab0 + s + 2) * 128 + srow];
    float l3 = lpart[(slab0 + s + 3) * 128 + srow];
    bf16x8 v0 = *(const bf16x8*)(opart + (slab0 + s + 0) * (128 * 128) + srow * 128 + colo);
    bf16x8 v1 = *(const bf16x8*)(opart + (slab0 + s + 1) * (128 * 128) + srow * 128 + colo);
    bf16x8 v2 = *(const bf16x8*)(opart + (slab0 + s + 2) * (128 * 128) + srow * 128 + colo);
    bf16x8 v3 = *(const bf16x8*)(opart + (slab0 + s + 3) * (128 * 128) + srow * 128 + colo);
    L += (l0 + l1) + (l2 + l3);
#pragma unroll
    for (int j = 0; j < 8; ++j)
      acc[j] += ((float)v0[j] + (float)v1[j]) + ((float)v2[j] + (float)v3[j]);
  }
  for (; s < ns; ++s) {
    L += lpart[(slab0 + s) * 128 + srow];
    bf16x8 ov = *(const bf16x8*)(opart + (slab0 + s) * (128 * 128) + srow * 128 + colo);
#pragma unroll
    for (int j = 0; j < 8; ++j) acc[j] += (float)ov[j];
  }
  float invL = 1.f / L;
  float* o = out + ((size_t)(b * TT + qt16 * 16 + row)) * HH + colo;
  f32x4 o0, o1;
#pragma unroll
  for (int j = 0; j < 4; ++j) { o0[j] = acc[j] * invL; o1[j] = acc[j + 4] * invL; }
  *(f32x4*)o = o0;
  *(f32x4*)(o + 4) = o1;
}

extern "C" void kernel_launch(void* const* d_in, const int* in_sizes, int n_in,
                              void* d_out, int out_size, void* d_ws, size_t ws_size,
                              hipStream_t stream) {
  const float* x = (const float*)d_in[0];
  const float* wq = (const float*)d_in[1];
  const float* wk = (const float*)d_in[2];
  const float* wv = (const float*)d_in[3];
  float* out = (float*)d_out;

  char* ws = (char*)d_ws;
  const size_t NE = (size_t)BB * TT * HH;  // 2,097,152
  bf16* wt = (bf16*)ws;                    // 768 KB
  bf16* q = (bf16*)(ws + (1 << 20));       // 4 MiB each
  bf16* k = q + NE;
  bf16* vt = k + NE;                       // V written pre-transposed by gemm
  bf16* opart = (bf16*)(ws + (16 << 20));  // 18.9 MiB
  float* lpart = (float*)(opart + (size_t)(BB * NSLAB) * 128 * 128);
  // total ws use: ~36 MiB

  wt_kernel<<<dim3(16, 2, 3), 256, 0, stream>>>(wq, wk, wv, wt);
  gemm_kernel<<<dim3(128, 4), 256, 0, stream>>>(x, wt, q, k, vt);
  flash_kernel<<<dim3(576), 256, 0, stream>>>(q, k, vt, opart, lpart);
  combine_kernel<<<dim3(8, 128, 2), 128, 0, stream>>>(opart, lpart, out);
}

// Round 11
// 156.818 us; speedup vs baseline: 1.0231x; 1.0015x over previous
//
#include <hip/hip_runtime.h>

#define BB 8
#define TT 2048
#define EE 1024
#define HH 128

typedef __bf16 bf16;
typedef __attribute__((ext_vector_type(8))) __bf16 bf16x8;
typedef __attribute__((ext_vector_type(4))) __bf16 bf16x4;
typedef __attribute__((ext_vector_type(4))) float f32x4;
typedef __attribute__((ext_vector_type(16))) float f32x16;

__device__ __host__ inline int qb_off(int qb) {
  int h = qb >> 1;
  return qb + h * (h - 1) + ((qb & 1) ? h : 0);
}
#define NSLAB 72  // qb_off(16); valid (qb,s) pairs per batch

__device__ inline void gload_lds16(const bf16* g, bf16* l) {
  __builtin_amdgcn_global_load_lds((const __attribute__((address_space(1))) unsigned int*)g,
                                   (__attribute__((address_space(3))) unsigned int*)l,
                                   16, 0, 0);
}

// ---- prep: fused {x fp32->bf16 cvt} + {Wt transpose} in one launch ----
// blocks 0..4095: xcvt role; blocks 4096..4191: wt role (whole-block split).
__global__ __launch_bounds__(256) void prep_kernel(const float* __restrict__ x,
                                                   bf16* __restrict__ xb,
                                                   const float* __restrict__ wq,
                                                   const float* __restrict__ wk,
                                                   const float* __restrict__ wv,
                                                   bf16* __restrict__ wt) {
  __shared__ float tile[64][65];
  const int bid = blockIdx.x;
  if (bid < 4096) {
    // x fp32 -> bf16 (memory-bound, coalesced)
    const size_t base = (size_t)bid * 4096 + threadIdx.x * 4;
#pragma unroll
    for (int j = 0; j < 4; ++j) {
      size_t idx = base + j * 1024;
      f32x4 xv = *(const f32x4*)(x + idx);
      bf16x4 xo;
#pragma unroll
      for (int i = 0; i < 4; ++i) xo[i] = (bf16)xv[i];
      *(bf16x4*)(xb + idx) = xo;
    }
  } else {
    // Wt[z*128+n][k] = W_z[k][n], fp32->bf16, LDS transpose
    const int id = bid - 4096;
    const int z = id >> 5;
    const int h0 = ((id >> 4) & 1) * 64;
    const int k0 = (id & 15) * 64;
    const float* w = (z == 0) ? wq : ((z == 1) ? wk : wv);
    const int c = threadIdx.x & 63;
    const int r0 = threadIdx.x >> 6;
#pragma unroll
    for (int i = 0; i < 16; ++i) {
      int tt = r0 + i * 4;
      tile[tt][c] = w[(size_t)(k0 + tt) * HH + h0 + c];
    }
    __syncthreads();
#pragma unroll
    for (int i = 0; i < 16; ++i) {
      int hh = r0 + i * 4;
      wt[((size_t)(z * HH + h0 + hh)) * EE + k0 + c] = (bf16)tile[c][hh];
    }
  }
}

// ---- fused qkv GEMM, 2-phase LDS double-buffer; epilogue writes q,k ----
// row-major and V DIRECTLY TRANSPOSED into vt. grid (4,128): the four
// blocks sharing an A-panel (256KB xb) are dispatch-adjacent -> warm L2/L3.
__global__ __launch_bounds__(256) void gemm_kernel(const bf16* __restrict__ xb,
                                                   const bf16* __restrict__ wt,
                                                   bf16* __restrict__ q,
                                                   bf16* __restrict__ k,
                                                   bf16* __restrict__ vt) {
  __shared__ bf16 As[2][128 * 32];  // 16 KB
  __shared__ bf16 Bs[2][96 * 32];   // 12 KB
  const int tid = threadIdx.x;
  const int lane = tid & 63;
  const int wave = tid >> 6;
  const int l16 = lane & 15;
  const int quad = lane >> 4;
  const int wm = wave & 1;   // M half (64 rows)
  const int wn = wave >> 1;  // N half (48 cols)
  const int ntile = blockIdx.x;  // 0..3
  const int bm = blockIdx.y;     // 0..127

  const int trow = tid >> 2;        // 0..63
  const int tsub = (tid & 3) * 8;   // 0,8,16,24
  const bf16* gA = xb + (size_t)(bm * 128 + trow) * EE + tsub;
  const bf16* gB = wt + (size_t)(ntile * 96 + trow) * EE + tsub;

  f32x4 acc[4][3];
#pragma unroll
  for (int rg = 0; rg < 4; ++rg)
#pragma unroll
    for (int nt = 0; nt < 3; ++nt) acc[rg][nt] = f32x4{0.f, 0.f, 0.f, 0.f};

  auto stage = [&](int bufi, int ks) {
    gload_lds16(gA + ks * 32, &As[bufi][wave * 512]);
    gload_lds16(gA + (size_t)64 * EE + ks * 32, &As[bufi][2048 + wave * 512]);
    gload_lds16(gB + ks * 32, &Bs[bufi][wave * 512]);
    if (tid < 128)
      gload_lds16(gB + (size_t)64 * EE + ks * 32, &Bs[bufi][2048 + wave * 512]);
  };

  stage(0, 0);
  __syncthreads();  // prologue drain: buf0 staged

  int buf = 0;
  for (int ks = 0; ks < EE / 32; ++ks) {
    if (ks < EE / 32 - 1) stage(buf ^ 1, ks + 1);  // issue next tile early

    bf16x8 af[4], bf_[3];
#pragma unroll
    for (int rg = 0; rg < 4; ++rg)
      af[rg] = *(const bf16x8*)&As[buf][(wm * 64 + rg * 16 + l16) * 32 + quad * 8];
#pragma unroll
    for (int nt = 0; nt < 3; ++nt)
      bf_[nt] = *(const bf16x8*)&Bs[buf][(wn * 48 + nt * 16 + l16) * 32 + quad * 8];
#pragma unroll
    for (int rg = 0; rg < 4; ++rg)
#pragma unroll
      for (int nt = 0; nt < 3; ++nt)
        acc[rg][nt] = __builtin_amdgcn_mfma_f32_16x16x32_bf16(af[rg], bf_[nt], acc[rg][nt], 0, 0, 0);

    __syncthreads();  // drains vmcnt(0) AFTER compute; readers done before restage
    buf ^= 1;
  }

#pragma unroll
  for (int rg = 0; rg < 4; ++rg)
#pragma unroll
    for (int nt = 0; nt < 3; ++nt) {
      int col = ntile * 96 + wn * 48 + nt * 16 + l16;
      int z = col >> 7;          // wave-uniform (col base 16-aligned)
      int n = col & 127;
      int row0 = bm * 128 + wm * 64 + rg * 16 + quad * 4;
      if (z == 2) {
        // V: write transposed. 4 consecutive t at fixed h -> 8B store.
        int bb = row0 >> 11;
        int t0 = row0 & (TT - 1);
        bf16x4 pkv;
#pragma unroll
        for (int r = 0; r < 4; ++r) pkv[r] = (bf16)acc[rg][nt][r];
        *(bf16x4*)&vt[((size_t)(bb * HH + n)) * TT + t0] = pkv;
      } else {
        bf16* op = (z == 0) ? q : k;
#pragma unroll
        for (int r = 0; r < 4; ++r)
          op[(size_t)(row0 + r) * HH + n] = (bf16)acc[rg][nt][r];
      }
    }
}

// ---- flash v4 (session-best config): LDS-shared K/V double-buffered, ----
// ---- 2-phase prefetch, in-register softmax (T12), 2 blocks/CU.      ----
__device__ __forceinline__ unsigned pk2(float a, float b) {
  union { __bf16 h[2]; unsigned u; } x;
  x.h[0] = (__bf16)a;
  x.h[1] = (__bf16)b;
  return x.u;
}

// v_permlane32_swap_b32: vdst.hi(lanes 32-63) <-> vsrc.lo(lanes 0-31)
__device__ __forceinline__ void plswap(unsigned& a, unsigned& b) {
  asm volatile("v_permlane32_swap_b32 %0, %1" : "+v"(a), "+v"(b));
}

__global__ __launch_bounds__(256, 2) void flash_kernel(const bf16* __restrict__ q,
                                                       const bf16* __restrict__ k,
                                                       const bf16* __restrict__ vt,
                                                       bf16* __restrict__ opart,
                                                       float* __restrict__ lpart) {
  __shared__ bf16 Ks[2][64 * 128];  // [k-row 64][h 128], byte^=((r&7)<<4) swizzle
  __shared__ bf16 Vs[2][128 * 64];  // [h 128][t 64],     byte^=((h&7)<<4) swizzle

  const int b = blockIdx.x & 7;
  int j = (NSLAB - 1) - (blockIdx.x >> 3);  // heavy (high-qb) blocks first
  int qb = 0, ns = 1;
  while (j >= ns) { j -= ns; ++qb; ns = ((2 * qb + 1) >> 2) + 1; }
  const int s = j;
  const int kt0 = s * 4;
  const int kt1 = min(kt0 + 3, 2 * qb + 1);

  const int tid = threadIdx.x;
  const int lane = tid & 63;
  const int wave = tid >> 6;
  const int l32 = lane & 31;
  const int hi = lane >> 5;
  const int qrow = qb * 128 + wave * 32 + l32;
  const int kdiag = qb * 4 + wave;  // diagonal 32-block for this wave

  // Q fragments: lane holds q-row = l&31 (B-operand of swapped QK^T)
  bf16x8 qf[8];
  {
    const bf16* qp = q + (size_t)(b * TT + qrow) * HH + hi * 8;
#pragma unroll
    for (int h16 = 0; h16 < 8; ++h16) qf[h16] = *(const bf16x8*)(qp + h16 * 16);
  }

  f32x16 O[4];
#pragma unroll
  for (int ht = 0; ht < 4; ++ht)
#pragma unroll
    for (int r = 0; r < 16; ++r) O[ht][r] = 0.f;
  float L = 0.f;

  // staging source mapping (pre-swizzled so linear LDS + swizzled read match)
  const int krow_s = tid >> 4;                    // K: row within 16-row round
  const int kchk_s = (tid & 15) ^ (krow_s & 7);   // 16B chunk, inverse-swizzled
  const int vrow_s = tid >> 3;                    // V: row within 32-row round
  const int vchk_s = (tid & 7) ^ (vrow_s & 7);
  const bf16* kg = k + (size_t)b * TT * HH;
  const bf16* vg = vt + (size_t)b * HH * TT;

  auto stageKV = [&](int bufi, int kt) {
#pragma unroll
    for (int i = 0; i < 4; ++i)
      gload_lds16(kg + (size_t)(kt * 64 + i * 16 + krow_s) * HH + kchk_s * 8,
                  &Ks[bufi][(i * 256 + wave * 64) * 8]);
#pragma unroll
    for (int i = 0; i < 4; ++i)
      gload_lds16(vg + (size_t)(i * 32 + vrow_s) * TT + kt * 64 + vchk_s * 8,
                  &Vs[bufi][(i * 256 + wave * 64) * 8]);
  };

  const int kxor = (l32 & 7) << 3;        // read-side XOR, element units
  const float c_ = 0.12753257680406733f;  // log2(e)/sqrt(128)

  stageKV(0, kt0);
  __syncthreads();  // prologue drain: buf0 staged

  int buf = 0;
  for (int kt = kt0; kt <= kt1; ++kt) {
    if (kt < kt1) stageKV(buf ^ 1, kt + 1);  // issue next tile early

#pragma unroll
    for (int khalf = 0; khalf < 2; ++khalf) {
      const int k32 = kt * 2 + khalf;
      if (k32 <= kdiag) {
        // K fragments from LDS (swizzled read)
        const bf16* kls = &Ks[buf][(khalf * 32 + l32) * 128];
        bf16x8 kf[8];
#pragma unroll
        for (int h16 = 0; h16 < 8; ++h16)
          kf[h16] = *(const bf16x8*)&kls[(h16 * 16 + hi * 8) ^ kxor];

        // S^T[k][q] = K . Q^T  (lane: q=l&31; regs: k=(r&3)+8*(r>>2)+4*hi)
        f32x16 S;
#pragma unroll
        for (int r = 0; r < 16; ++r) S[r] = 0.f;
        __builtin_amdgcn_s_setprio(1);
#pragma unroll
        for (int h16 = 0; h16 < 8; ++h16)
          S = __builtin_amdgcn_mfma_f32_32x32x16_bf16(kf[h16], qf[h16], S, 0, 0, 0);
        __builtin_amdgcn_s_setprio(0);

        // softmax (no-max; scale folded into exp2), in registers
        float p[16];
        if (k32 == kdiag) {
          const int kkb = k32 * 32 + 4 * hi;
#pragma unroll
          for (int r = 0; r < 16; ++r) {
            int kk = kkb + (r & 3) + 8 * (r >> 2);
            float pv = (kk <= qrow) ? exp2f(S[r] * c_) : 0.f;
            p[r] = pv;
            L += pv;
          }
        } else {
#pragma unroll
          for (int r = 0; r < 16; ++r) {
            float pv = exp2f(S[r] * c_);
            p[r] = pv;
            L += pv;
          }
        }

        // P -> bf16 A-frag (pack + permlane32_swap, T12), then PV from LDS V
#pragma unroll
        for (int s16 = 0; s16 < 2; ++s16) {
          unsigned w0 = pk2(p[s16 * 8 + 0], p[s16 * 8 + 1]);
          unsigned w1 = pk2(p[s16 * 8 + 2], p[s16 * 8 + 3]);
          unsigned w2 = pk2(p[s16 * 8 + 4], p[s16 * 8 + 5]);
          unsigned w3 = pk2(p[s16 * 8 + 6], p[s16 * 8 + 7]);
          plswap(w0, w2);
          plswap(w1, w3);
          union { unsigned u[4]; bf16x8 v; } af;
          af.u[0] = w0;
          af.u[1] = w1;
          af.u[2] = w2;
          af.u[3] = w3;
          bf16x8 vf[4];
#pragma unroll
          for (int ht = 0; ht < 4; ++ht)
            vf[ht] = *(const bf16x8*)&Vs[buf][(l32 + 32 * ht) * 64 +
                                             ((khalf * 32 + s16 * 16 + hi * 8) ^ kxor)];
          __builtin_amdgcn_s_setprio(1);
#pragma unroll
          for (int ht = 0; ht < 4; ++ht)
            O[ht] = __builtin_amdgcn_mfma_f32_32x32x16_bf16(af.v, vf[ht], O[ht], 0, 0, 0);
          __builtin_amdgcn_s_setprio(0);
        }
      }
    }
    __syncthreads();  // drains vmcnt(0) after compute; readers done before restage
    buf ^= 1;
  }

  L += __shfl_xor(L, 32, 64);  // partner half holds complementary k-subset

  const size_t slab = (size_t)(b * NSLAB + qb_off(qb) + s);
  bf16* op = opart + slab * (128 * 128) + (size_t)wave * 32 * 128;
#pragma unroll
  for (int ht = 0; ht < 4; ++ht)
#pragma unroll
    for (int r = 0; r < 16; ++r) {
      int qr = (r & 3) + 8 * (r >> 2) + 4 * hi;
      op[qr * 128 + ht * 32 + l32] = (bf16)O[ht][r];
    }
  if (hi == 0) lpart[slab * 128 + wave * 32 + l32] = L;
}

// ---- combine: grid (b, qt16, half) -> 2048 blocks of 128 thr ----
__global__ __launch_bounds__(128) void combine_kernel(const bf16* __restrict__ opart,
                                                      const float* __restrict__ lpart,
                                                      float* __restrict__ out) {
  const int b = blockIdx.x;
  const int qt16 = blockIdx.y;
  const int half = blockIdx.z;
  const int row = threadIdx.x >> 3;
  const int colo = (threadIdx.x & 7) * 8 + half * 64;
  const int qb = qt16 >> 3;
  const int srow = (qt16 & 7) * 16 + row;
  const int ns = ((2 * qb + 1) >> 2) + 1;  // 1..8
  const size_t slab0 = (size_t)(b * NSLAB + qb_off(qb));

  float acc[8];
#pragma unroll
  for (int j = 0; j < 8; ++j) acc[j] = 0.f;
  float L = 0.f;

  int s = 0;
  for (; s + 4 <= ns; s += 4) {
    float l0 = lpart[(slab0 + s + 0) * 128 + srow];
    float l1 = lpart[(slab0 + s + 1) * 128 + srow];
    float l2 = lpart[(slab0 + s + 2) * 128 + srow];
    float l3 = lpart[(slab0 + s + 3) * 128 + srow];
    bf16x8 v0 = *(const bf16x8*)(opart + (slab0 + s + 0) * (128 * 128) + srow * 128 + colo);
    bf16x8 v1 = *(const bf16x8*)(opart + (slab0 + s + 1) * (128 * 128) + srow * 128 + colo);
    bf16x8 v2 = *(const bf16x8*)(opart + (slab0 + s + 2) * (128 * 128) + srow * 128 + colo);
    bf16x8 v3 = *(const bf16x8*)(opart + (slab0 + s + 3) * (128 * 128) + srow * 128 + colo);
    L += (l0 + l1) + (l2 + l3);
#pragma unroll
    for (int j = 0; j < 8; ++j)
      acc[j] += ((float)v0[j] + (float)v1[j]) + ((float)v2[j] + (float)v3[j]);
  }
  for (; s < ns; ++s) {
    L += lpart[(slab0 + s) * 128 + srow];
    bf16x8 ov = *(const bf16x8*)(opart + (slab0 + s) * (128 * 128) + srow * 128 + colo);
#pragma unroll
    for (int j = 0; j < 8; ++j) acc[j] += (float)ov[j];
  }
  float invL = 1.f / L;
  float* o = out + ((size_t)(b * TT + qt16 * 16 + row)) * HH + colo;
  f32x4 o0, o1;
#pragma unroll
  for (int j = 0; j < 4; ++j) { o0[j] = acc[j] * invL; o1[j] = acc[j + 4] * invL; }
  *(f32x4*)o = o0;
  *(f32x4*)(o + 4) = o1;
}

extern "C" void kernel_launch(void* const* d_in, const int* in_sizes, int n_in,
                              void* d_out, int out_size, void* d_ws, size_t ws_size,
                              hipStream_t stream) {
  const float* x = (const float*)d_in[0];
  const float* wq = (const float*)d_in[1];
  const float* wk = (const float*)d_in[2];
  const float* wv = (const float*)d_in[3];
  float* out = (float*)d_out;

  char* ws = (char*)d_ws;
  const size_t NE = (size_t)BB * TT * HH;  // 2,097,152
  bf16* wt = (bf16*)ws;                    // 768 KB
  bf16* xb = (bf16*)(ws + (1 << 20));      // 32 MiB (16384x1024 bf16)
  bf16* q = (bf16*)(ws + (33 << 20));      // 4 MiB each
  bf16* k = q + NE;
  bf16* vt = k + NE;                       // V written pre-transposed by gemm
  // xb is dead after gemm; opart/lpart alias its region (19.2 MB < 32 MiB)
  bf16* opart = xb;
  float* lpart = (float*)(opart + (size_t)(BB * NSLAB) * 128 * 128);
  // total ws use: 45 MiB

  prep_kernel<<<dim3(4192), 256, 0, stream>>>(x, xb, wq, wk, wv, wt);
  gemm_kernel<<<dim3(4, 128), 256, 0, stream>>>(xb, wt, q, k, vt);
  flash_kernel<<<dim3(576), 256, 0, stream>>>(q, k, vt, opart, lpart);
  combine_kernel<<<dim3(8, 128, 2), 128, 0, stream>>>(opart, lpart, out);
}

// Round 12
// 154.519 us; speedup vs baseline: 1.0383x; 1.0149x over previous
//
#include <hip/hip_runtime.h>

#define BB 8
#define TT 2048
#define EE 1024
#define HH 128

typedef __bf16 bf16;
typedef __attribute__((ext_vector_type(8))) __bf16 bf16x8;
typedef __attribute__((ext_vector_type(4))) __bf16 bf16x4;
typedef __attribute__((ext_vector_type(4))) float f32x4;
typedef __attribute__((ext_vector_type(16))) float f32x16;

__device__ __host__ inline int qb_off(int qb) {
  int h = qb >> 1;
  return qb + h * (h - 1) + ((qb & 1) ? h : 0);
}
#define NSLAB 72  // qb_off(16); valid (qb,s) pairs per batch

__device__ inline void gload_lds16(const bf16* g, bf16* l) {
  __builtin_amdgcn_global_load_lds((const __attribute__((address_space(1))) unsigned int*)g,
                                   (__attribute__((address_space(3))) unsigned int*)l,
                                   16, 0, 0);
}

#define SBAR() asm volatile("s_barrier" ::: "memory")

// ---- prep: fused {x fp32->bf16 cvt} + {Wt transpose} in one launch ----
// blocks 0..4095: xcvt role; blocks 4096..4191: wt role (whole-block split).
__global__ __launch_bounds__(256) void prep_kernel(const float* __restrict__ x,
                                                   bf16* __restrict__ xb,
                                                   const float* __restrict__ wq,
                                                   const float* __restrict__ wk,
                                                   const float* __restrict__ wv,
                                                   bf16* __restrict__ wt) {
  __shared__ float tile[64][65];
  const int bid = blockIdx.x;
  if (bid < 4096) {
    // x fp32 -> bf16 (memory-bound, coalesced)
    const size_t base = (size_t)bid * 4096 + threadIdx.x * 4;
#pragma unroll
    for (int j = 0; j < 4; ++j) {
      size_t idx = base + j * 1024;
      f32x4 xv = *(const f32x4*)(x + idx);
      bf16x4 xo;
#pragma unroll
      for (int i = 0; i < 4; ++i) xo[i] = (bf16)xv[i];
      *(bf16x4*)(xb + idx) = xo;
    }
  } else {
    // Wt[z*128+n][k] = W_z[k][n], fp32->bf16, LDS transpose
    const int id = bid - 4096;
    const int z = id >> 5;
    const int h0 = ((id >> 4) & 1) * 64;
    const int k0 = (id & 15) * 64;
    const float* w = (z == 0) ? wq : ((z == 1) ? wk : wv);
    const int c = threadIdx.x & 63;
    const int r0 = threadIdx.x >> 6;
#pragma unroll
    for (int i = 0; i < 16; ++i) {
      int tt = r0 + i * 4;
      tile[tt][c] = w[(size_t)(k0 + tt) * HH + h0 + c];
    }
    __syncthreads();
#pragma unroll
    for (int i = 0; i < 16; ++i) {
      int hh = r0 + i * 4;
      wt[((size_t)(z * HH + h0 + hh)) * EE + k0 + c] = (bf16)tile[c][hh];
    }
  }
}

// ---- fused qkv GEMM, 2-phase dbuf + COUNTED vmcnt (T4): the wait at ----
// each iteration covers only the PREVIOUS tile's loads (issued a full ----
// iteration earlier), never the just-issued prefetch. Raw s_barrier   ----
// (no vmcnt(0) drain). V written pre-transposed into vt.              ----
__global__ __launch_bounds__(256) void gemm_kernel(const bf16* __restrict__ xb,
                                                   const bf16* __restrict__ wt,
                                                   bf16* __restrict__ q,
                                                   bf16* __restrict__ k,
                                                   bf16* __restrict__ vt) {
  __shared__ bf16 As[2][128 * 32];  // 16 KB
  __shared__ bf16 Bs[2][96 * 32];   // 12 KB
  const int tid = threadIdx.x;
  const int lane = tid & 63;
  const int wave = tid >> 6;
  const int l16 = lane & 15;
  const int quad = lane >> 4;
  const int wm = wave & 1;   // M half (64 rows)
  const int wn = wave >> 1;  // N half (48 cols)
  const int bm = blockIdx.x;
  const int ntile = blockIdx.y;

  const int trow = tid >> 2;        // 0..63
  const int tsub = (tid & 3) * 8;   // 0,8,16,24
  const bf16* gA = xb + (size_t)(bm * 128 + trow) * EE + tsub;
  const bf16* gB = wt + (size_t)(ntile * 96 + trow) * EE + tsub;

  f32x4 acc[4][3];
#pragma unroll
  for (int rg = 0; rg < 4; ++rg)
#pragma unroll
    for (int nt = 0; nt < 3; ++nt) acc[rg][nt] = f32x4{0.f, 0.f, 0.f, 0.f};

  auto stage = [&](int bufi, int ks) {
    gload_lds16(gA + ks * 32, &As[bufi][wave * 512]);
    gload_lds16(gA + (size_t)64 * EE + ks * 32, &As[bufi][2048 + wave * 512]);
    gload_lds16(gB + ks * 32, &Bs[bufi][wave * 512]);
    if (tid < 128)
      gload_lds16(gB + (size_t)64 * EE + ks * 32, &Bs[bufi][2048 + wave * 512]);
  };

  stage(0, 0);  // prologue issue; loop-top wait/barrier publishes it

  int buf = 0;
  for (int ks = 0; ks < EE / 32; ++ks) {
    if (ks < EE / 32 - 1) {
      stage(buf ^ 1, ks + 1);  // issue next tile (stays in flight across barrier)
      // wait only for the OLDEST loads = buf's tile (issued last iteration)
      if (tid < 128) { asm volatile("s_waitcnt vmcnt(4)" ::: "memory"); }
      else           { asm volatile("s_waitcnt vmcnt(3)" ::: "memory"); }
    } else {
      asm volatile("s_waitcnt vmcnt(0)" ::: "memory");
    }
    SBAR();  // all waves' buf-loads retired -> buf fully staged

    bf16x8 af[4], bf_[3];
#pragma unroll
    for (int rg = 0; rg < 4; ++rg)
      af[rg] = *(const bf16x8*)&As[buf][(wm * 64 + rg * 16 + l16) * 32 + quad * 8];
#pragma unroll
    for (int nt = 0; nt < 3; ++nt)
      bf_[nt] = *(const bf16x8*)&Bs[buf][(wn * 48 + nt * 16 + l16) * 32 + quad * 8];
#pragma unroll
    for (int rg = 0; rg < 4; ++rg)
#pragma unroll
      for (int nt = 0; nt < 3; ++nt)
        acc[rg][nt] = __builtin_amdgcn_mfma_f32_16x16x32_bf16(af[rg], bf_[nt], acc[rg][nt], 0, 0, 0);

    SBAR();  // readers done before buf is restaged next iteration (no drain)
    buf ^= 1;
  }

#pragma unroll
  for (int rg = 0; rg < 4; ++rg)
#pragma unroll
    for (int nt = 0; nt < 3; ++nt) {
      int col = ntile * 96 + wn * 48 + nt * 16 + l16;
      int z = col >> 7;          // wave-uniform (col base 16-aligned)
      int n = col & 127;
      int row0 = bm * 128 + wm * 64 + rg * 16 + quad * 4;
      if (z == 2) {
        // V: write transposed. 4 consecutive t at fixed h -> 8B store.
        int bb = row0 >> 11;
        int t0 = row0 & (TT - 1);
        bf16x4 pkv;
#pragma unroll
        for (int r = 0; r < 4; ++r) pkv[r] = (bf16)acc[rg][nt][r];
        *(bf16x4*)&vt[((size_t)(bb * HH + n)) * TT + t0] = pkv;
      } else {
        bf16* op = (z == 0) ? q : k;
#pragma unroll
        for (int r = 0; r < 4; ++r)
          op[(size_t)(row0 + r) * HH + n] = (bf16)acc[rg][nt][r];
      }
    }
}

// ---- flash v8: K/V dbuf LDS + COUNTED vmcnt(8) (T4) + raw barriers; ----
// ---- in-register softmax (T12), 2 blocks/CU.                        ----
__device__ __forceinline__ unsigned pk2(float a, float b) {
  union { __bf16 h[2]; unsigned u; } x;
  x.h[0] = (__bf16)a;
  x.h[1] = (__bf16)b;
  return x.u;
}

// v_permlane32_swap_b32: vdst.hi(lanes 32-63) <-> vsrc.lo(lanes 0-31)
__device__ __forceinline__ void plswap(unsigned& a, unsigned& b) {
  asm volatile("v_permlane32_swap_b32 %0, %1" : "+v"(a), "+v"(b));
}

__global__ __launch_bounds__(256, 2) void flash_kernel(const bf16* __restrict__ q,
                                                       const bf16* __restrict__ k,
                                                       const bf16* __restrict__ vt,
                                                       bf16* __restrict__ opart,
                                                       float* __restrict__ lpart) {
  __shared__ bf16 Ks[2][64 * 128];  // [k-row 64][h 128], byte^=((r&7)<<4) swizzle
  __shared__ bf16 Vs[2][128 * 64];  // [h 128][t 64],     byte^=((h&7)<<4) swizzle

  const int b = blockIdx.x & 7;
  int j = (NSLAB - 1) - (blockIdx.x >> 3);  // heavy (high-qb) blocks first
  int qb = 0, ns = 1;
  while (j >= ns) { j -= ns; ++qb; ns = ((2 * qb + 1) >> 2) + 1; }
  const int s = j;
  const int kt0 = s * 4;
  const int kt1 = min(kt0 + 3, 2 * qb + 1);

  const int tid = threadIdx.x;
  const int lane = tid & 63;
  const int wave = tid >> 6;
  const int l32 = lane & 31;
  const int hi = lane >> 5;
  const int qrow = qb * 128 + wave * 32 + l32;
  const int kdiag = qb * 4 + wave;  // diagonal 32-block for this wave

  // Q fragments: lane holds q-row = l&31 (B-operand of swapped QK^T)
  bf16x8 qf[8];
  {
    const bf16* qp = q + (size_t)(b * TT + qrow) * HH + hi * 8;
#pragma unroll
    for (int h16 = 0; h16 < 8; ++h16) qf[h16] = *(const bf16x8*)(qp + h16 * 16);
  }

  f32x16 O[4];
#pragma unroll
  for (int ht = 0; ht < 4; ++ht)
#pragma unroll
    for (int r = 0; r < 16; ++r) O[ht][r] = 0.f;
  float L = 0.f;

  // staging source mapping (pre-swizzled so linear LDS + swizzled read match)
  const int krow_s = tid >> 4;                    // K: row within 16-row round
  const int kchk_s = (tid & 15) ^ (krow_s & 7);   // 16B chunk, inverse-swizzled
  const int vrow_s = tid >> 3;                    // V: row within 32-row round
  const int vchk_s = (tid & 7) ^ (vrow_s & 7);
  const bf16* kg = k + (size_t)b * TT * HH;
  const bf16* vg = vt + (size_t)b * HH * TT;

  auto stageKV = [&](int bufi, int kt) {
#pragma unroll
    for (int i = 0; i < 4; ++i)
      gload_lds16(kg + (size_t)(kt * 64 + i * 16 + krow_s) * HH + kchk_s * 8,
                  &Ks[bufi][(i * 256 + wave * 64) * 8]);
#pragma unroll
    for (int i = 0; i < 4; ++i)
      gload_lds16(vg + (size_t)(i * 32 + vrow_s) * TT + kt * 64 + vchk_s * 8,
                  &Vs[bufi][(i * 256 + wave * 64) * 8]);
  };

  const int kxor = (l32 & 7) << 3;        // read-side XOR, element units
  const float c_ = 0.12753257680406733f;  // log2(e)/sqrt(128)

  stageKV(0, kt0);  // prologue issue; loop-top wait/barrier publishes it

  int buf = 0;
  for (int kt = kt0; kt <= kt1; ++kt) {
    if (kt < kt1) {
      stageKV(buf ^ 1, kt + 1);  // 8 loads in flight across the barrier
      asm volatile("s_waitcnt vmcnt(8)" ::: "memory");  // oldest 8 = buf's tile
    } else {
      asm volatile("s_waitcnt vmcnt(0)" ::: "memory");
    }
    SBAR();  // all waves' buf-loads retired -> Ks/Vs[buf] fully staged

#pragma unroll
    for (int khalf = 0; khalf < 2; ++khalf) {
      const int k32 = kt * 2 + khalf;
      if (k32 <= kdiag) {
        // K fragments from LDS (swizzled read)
        const bf16* kls = &Ks[buf][(khalf * 32 + l32) * 128];
        bf16x8 kf[8];
#pragma unroll
        for (int h16 = 0; h16 < 8; ++h16)
          kf[h16] = *(const bf16x8*)&kls[(h16 * 16 + hi * 8) ^ kxor];

        // S^T[k][q] = K . Q^T  (lane: q=l&31; regs: k=(r&3)+8*(r>>2)+4*hi)
        f32x16 S;
#pragma unroll
        for (int r = 0; r < 16; ++r) S[r] = 0.f;
        __builtin_amdgcn_s_setprio(1);
#pragma unroll
        for (int h16 = 0; h16 < 8; ++h16)
          S = __builtin_amdgcn_mfma_f32_32x32x16_bf16(kf[h16], qf[h16], S, 0, 0, 0);
        __builtin_amdgcn_s_setprio(0);

        // softmax (no-max; scale folded into exp2), in registers
        float p[16];
        if (k32 == kdiag) {
          const int kkb = k32 * 32 + 4 * hi;
#pragma unroll
          for (int r = 0; r < 16; ++r) {
            int kk = kkb + (r & 3) + 8 * (r >> 2);
            float pv = (kk <= qrow) ? exp2f(S[r] * c_) : 0.f;
            p[r] = pv;
            L += pv;
          }
        } else {
#pragma unroll
          for (int r = 0; r < 16; ++r) {
            float pv = exp2f(S[r] * c_);
            p[r] = pv;
            L += pv;
          }
        }

        // P -> bf16 A-frag (pack + permlane32_swap, T12), then PV from LDS V
#pragma unroll
        for (int s16 = 0; s16 < 2; ++s16) {
          unsigned w0 = pk2(p[s16 * 8 + 0], p[s16 * 8 + 1]);
          unsigned w1 = pk2(p[s16 * 8 + 2], p[s16 * 8 + 3]);
          unsigned w2 = pk2(p[s16 * 8 + 4], p[s16 * 8 + 5]);
          unsigned w3 = pk2(p[s16 * 8 + 6], p[s16 * 8 + 7]);
          plswap(w0, w2);
          plswap(w1, w3);
          union { unsigned u[4]; bf16x8 v; } af;
          af.u[0] = w0;
          af.u[1] = w1;
          af.u[2] = w2;
          af.u[3] = w3;
          bf16x8 vf[4];
#pragma unroll
          for (int ht = 0; ht < 4; ++ht)
            vf[ht] = *(const bf16x8*)&Vs[buf][(l32 + 32 * ht) * 64 +
                                             ((khalf * 32 + s16 * 16 + hi * 8) ^ kxor)];
          __builtin_amdgcn_s_setprio(1);
#pragma unroll
          for (int ht = 0; ht < 4; ++ht)
            O[ht] = __builtin_amdgcn_mfma_f32_32x32x16_bf16(af.v, vf[ht], O[ht], 0, 0, 0);
          __builtin_amdgcn_s_setprio(0);
        }
      }
    }
    SBAR();  // readers done before buf is restaged next iteration (no drain)
    buf ^= 1;
  }

  L += __shfl_xor(L, 32, 64);  // partner half holds complementary k-subset

  const size_t slab = (size_t)(b * NSLAB + qb_off(qb) + s);
  bf16* op = opart + slab * (128 * 128) + (size_t)wave * 32 * 128;
#pragma unroll
  for (int ht = 0; ht < 4; ++ht)
#pragma unroll
    for (int r = 0; r < 16; ++r) {
      int qr = (r & 3) + 8 * (r >> 2) + 4 * hi;
      op[qr * 128 + ht * 32 + l32] = (bf16)O[ht][r];
    }
  if (hi == 0) lpart[slab * 128 + wave * 32 + l32] = L;
}

// ---- combine: grid (b, qt16, half) -> 2048 blocks of 128 thr ----
__global__ __launch_bounds__(128) void combine_kernel(const bf16* __restrict__ opart,
                                                      const float* __restrict__ lpart,
                                                      float* __restrict__ out) {
  const int b = blockIdx.x;
  const int qt16 = blockIdx.y;
  const int half = blockIdx.z;
  const int row = threadIdx.x >> 3;
  const int colo = (threadIdx.x & 7) * 8 + half * 64;
  const int qb = qt16 >> 3;
  const int srow = (qt16 & 7) * 16 + row;
  const int ns = ((2 * qb + 1) >> 2) + 1;  // 1..8
  const size_t slab0 = (size_t)(b * NSLAB + qb_off(qb));

  float acc[8];
#pragma unroll
  for (int j = 0; j < 8; ++j) acc[j] = 0.f;
  float L = 0.f;

  int s = 0;
  for (; s + 4 <= ns; s += 4) {
    float l0 = lpart[(slab0 + s + 0) * 128 + srow];
    float l1 = lpart[(slab0 + s + 1) * 128 + srow];
    float l2 = lpart[(slab0 + s + 2) * 128 + srow];
    float l3 = lpart[(slab0 + s + 3) * 128 + srow];
    bf16x8 v0 = *(const bf16x8*)(opart + (slab0 + s + 0) * (128 * 128) + srow * 128 + colo);
    bf16x8 v1 = *(const bf16x8*)(opart + (slab0 + s + 1) * (128 * 128) + srow * 128 + colo);
    bf16x8 v2 = *(const bf16x8*)(opart + (slab0 + s + 2) * (128 * 128) + srow * 128 + colo);
    bf16x8 v3 = *(const bf16x8*)(opart + (slab0 + s + 3) * (128 * 128) + srow * 128 + colo);
    L += (l0 + l1) + (l2 + l3);
#pragma unroll
    for (int j = 0; j < 8; ++j)
      acc[j] += ((float)v0[j] + (float)v1[j]) + ((float)v2[j] + (float)v3[j]);
  }
  for (; s < ns; ++s) {
    L += lpart[(slab0 + s) * 128 + srow];
    bf16x8 ov = *(const bf16x8*)(opart + (slab0 + s) * (128 * 128) + srow * 128 + colo);
#pragma unroll
    for (int j = 0; j < 8; ++j) acc[j] += (float)ov[j];
  }
  float invL = 1.f / L;
  float* o = out + ((size_t)(b * TT + qt16 * 16 + row)) * HH + colo;
  f32x4 o0, o1;
#pragma unroll
  for (int j = 0; j < 4; ++j) { o0[j] = acc[j] * invL; o1[j] = acc[j + 4] * invL; }
  *(f32x4*)o = o0;
  *(f32x4*)(o + 4) = o1;
}

extern "C" void kernel_launch(void* const* d_in, const int* in_sizes, int n_in,
                              void* d_out, int out_size, void* d_ws, size_t ws_size,
                              hipStream_t stream) {
  const float* x = (const float*)d_in[0];
  const float* wq = (const float*)d_in[1];
  const float* wk = (const float*)d_in[2];
  const float* wv = (const float*)d_in[3];
  float* out = (float*)d_out;

  char* ws = (char*)d_ws;
  const size_t NE = (size_t)BB * TT * HH;  // 2,097,152
  bf16* wt = (bf16*)ws;                    // 768 KB
  bf16* xb = (bf16*)(ws + (1 << 20));      // 32 MiB (16384x1024 bf16)
  bf16* q = (bf16*)(ws + (33 << 20));      // 4 MiB each
  bf16* k = q + NE;
  bf16* vt = k + NE;                       // V written pre-transposed by gemm
  // xb is dead after gemm; opart/lpart alias its region (19.2 MB < 32 MiB)
  bf16* opart = xb;
  float* lpart = (float*)(opart + (size_t)(BB * NSLAB) * 128 * 128);
  // total ws use: 45 MiB

  prep_kernel<<<dim3(4192), 256, 0, stream>>>(x, xb, wq, wk, wv, wt);
  gemm_kernel<<<dim3(128, 4), 256, 0, stream>>>(xb, wt, q, k, vt);
  flash_kernel<<<dim3(576), 256, 0, stream>>>(q, k, vt, opart, lpart);
  combine_kernel<<<dim3(8, 128, 2), 128, 0, stream>>>(opart, lpart, out);
}

// Round 13
// 152.132 us; speedup vs baseline: 1.0546x; 1.0157x over previous
//
#include <hip/hip_runtime.h>

#define BB 8
#define TT 2048
#define EE 1024
#define HH 128

typedef __bf16 bf16;
typedef __attribute__((ext_vector_type(8))) __bf16 bf16x8;
typedef __attribute__((ext_vector_type(4))) __bf16 bf16x4;
typedef __attribute__((ext_vector_type(4))) float f32x4;
typedef __attribute__((ext_vector_type(16))) float f32x16;

__device__ __host__ inline int qb_off(int qb) {
  int h = qb >> 1;
  return qb + h * (h - 1) + ((qb & 1) ? h : 0);
}
#define NSLAB 72  // qb_off(16); valid (qb,s) pairs per batch

__device__ inline void gload_lds16(const bf16* g, bf16* l) {
  __builtin_amdgcn_global_load_lds((const __attribute__((address_space(1))) unsigned int*)g,
                                   (__attribute__((address_space(3))) unsigned int*)l,
                                   16, 0, 0);
}

// ---- prep: fused {x fp32->bf16 cvt} + {Wt transpose} in one launch ----
// blocks 0..4095: xcvt role; blocks 4096..4191: wt role (whole-block split).
__global__ __launch_bounds__(256) void prep_kernel(const float* __restrict__ x,
                                                   bf16* __restrict__ xb,
                                                   const float* __restrict__ wq,
                                                   const float* __restrict__ wk,
                                                   const float* __restrict__ wv,
                                                   bf16* __restrict__ wt) {
  __shared__ float tile[64][65];
  const int bid = blockIdx.x;
  if (bid < 4096) {
    // x fp32 -> bf16 (memory-bound, coalesced)
    const size_t base = (size_t)bid * 4096 + threadIdx.x * 4;
#pragma unroll
    for (int j = 0; j < 4; ++j) {
      size_t idx = base + j * 1024;
      f32x4 xv = *(const f32x4*)(x + idx);
      bf16x4 xo;
#pragma unroll
      for (int i = 0; i < 4; ++i) xo[i] = (bf16)xv[i];
      *(bf16x4*)(xb + idx) = xo;
    }
  } else {
    // Wt[z*128+n][k] = W_z[k][n], fp32->bf16, LDS transpose
    const int id = bid - 4096;
    const int z = id >> 5;
    const int h0 = ((id >> 4) & 1) * 64;
    const int k0 = (id & 15) * 64;
    const float* w = (z == 0) ? wq : ((z == 1) ? wk : wv);
    const int c = threadIdx.x & 63;
    const int r0 = threadIdx.x >> 6;
#pragma unroll
    for (int i = 0; i < 16; ++i) {
      int tt = r0 + i * 4;
      tile[tt][c] = w[(size_t)(k0 + tt) * HH + h0 + c];
    }
    __syncthreads();
#pragma unroll
    for (int i = 0; i < 16; ++i) {
      int hh = r0 + i * 4;
      wt[((size_t)(z * HH + h0 + hh)) * EE + k0 + c] = (bf16)tile[c][hh];
    }
  }
}

// ---- fused qkv GEMM, 2-phase LDS double-buffer; epilogue writes q,k ----
// row-major and V DIRECTLY TRANSPOSED into vt (thread holds 4 consecutive
// t at fixed h -> one aligned 8B bf16x4 store). vtrans kernel eliminated.
__global__ __launch_bounds__(256) void gemm_kernel(const bf16* __restrict__ xb,
                                                   const bf16* __restrict__ wt,
                                                   bf16* __restrict__ q,
                                                   bf16* __restrict__ k,
                                                   bf16* __restrict__ vt) {
  __shared__ bf16 As[2][128 * 32];  // 16 KB
  __shared__ bf16 Bs[2][96 * 32];   // 12 KB
  const int tid = threadIdx.x;
  const int lane = tid & 63;
  const int wave = tid >> 6;
  const int l16 = lane & 15;
  const int quad = lane >> 4;
  const int wm = wave & 1;   // M half (64 rows)
  const int wn = wave >> 1;  // N half (48 cols)
  const int bm = blockIdx.x;
  const int ntile = blockIdx.y;

  const int trow = tid >> 2;        // 0..63
  const int tsub = (tid & 3) * 8;   // 0,8,16,24
  const bf16* gA = xb + (size_t)(bm * 128 + trow) * EE + tsub;
  const bf16* gB = wt + (size_t)(ntile * 96 + trow) * EE + tsub;

  f32x4 acc[4][3];
#pragma unroll
  for (int rg = 0; rg < 4; ++rg)
#pragma unroll
    for (int nt = 0; nt < 3; ++nt) acc[rg][nt] = f32x4{0.f, 0.f, 0.f, 0.f};

  auto stage = [&](int bufi, int ks) {
    gload_lds16(gA + ks * 32, &As[bufi][wave * 512]);
    gload_lds16(gA + (size_t)64 * EE + ks * 32, &As[bufi][2048 + wave * 512]);
    gload_lds16(gB + ks * 32, &Bs[bufi][wave * 512]);
    if (tid < 128)
      gload_lds16(gB + (size_t)64 * EE + ks * 32, &Bs[bufi][2048 + wave * 512]);
  };

  stage(0, 0);
  __syncthreads();  // prologue drain: buf0 staged

  int buf = 0;
  for (int ks = 0; ks < EE / 32; ++ks) {
    if (ks < EE / 32 - 1) stage(buf ^ 1, ks + 1);  // issue next tile early

    bf16x8 af[4], bf_[3];
#pragma unroll
    for (int rg = 0; rg < 4; ++rg)
      af[rg] = *(const bf16x8*)&As[buf][(wm * 64 + rg * 16 + l16) * 32 + quad * 8];
#pragma unroll
    for (int nt = 0; nt < 3; ++nt)
      bf_[nt] = *(const bf16x8*)&Bs[buf][(wn * 48 + nt * 16 + l16) * 32 + quad * 8];
#pragma unroll
    for (int rg = 0; rg < 4; ++rg)
#pragma unroll
      for (int nt = 0; nt < 3; ++nt)
        acc[rg][nt] = __builtin_amdgcn_mfma_f32_16x16x32_bf16(af[rg], bf_[nt], acc[rg][nt], 0, 0, 0);

    __syncthreads();  // drains vmcnt(0) AFTER compute; readers done before restage
    buf ^= 1;
  }

#pragma unroll
  for (int rg = 0; rg < 4; ++rg)
#pragma unroll
    for (int nt = 0; nt < 3; ++nt) {
      int col = ntile * 96 + wn * 48 + nt * 16 + l16;
      int z = col >> 7;          // wave-uniform (col base 16-aligned)
      int n = col & 127;
      int row0 = bm * 128 + wm * 64 + rg * 16 + quad * 4;
      if (z == 2) {
        // V: write transposed. 4 consecutive t at fixed h -> 8B store.
        int bb = row0 >> 11;
        int t0 = row0 & (TT - 1);
        bf16x4 pkv;
#pragma unroll
        for (int r = 0; r < 4; ++r) pkv[r] = (bf16)acc[rg][nt][r];
        *(bf16x4*)&vt[((size_t)(bb * HH + n)) * TT + t0] = pkv;
      } else {
        bf16* op = (z == 0) ? q : k;
#pragma unroll
        for (int r = 0; r < 4; ++r)
          op[(size_t)(row0 + r) * HH + n] = (bf16)acc[rg][nt][r];
      }
    }
}

// ---- flash v4 (session-best, 153.66us total): LDS-shared K/V double- ----
// ---- buffered, 2-phase prefetch, in-register softmax (T12), 2/CU.   ----
__device__ __forceinline__ unsigned pk2(float a, float b) {
  union { __bf16 h[2]; unsigned u; } x;
  x.h[0] = (__bf16)a;
  x.h[1] = (__bf16)b;
  return x.u;
}

// v_permlane32_swap_b32: vdst.hi(lanes 32-63) <-> vsrc.lo(lanes 0-31)
__device__ __forceinline__ void plswap(unsigned& a, unsigned& b) {
  asm volatile("v_permlane32_swap_b32 %0, %1" : "+v"(a), "+v"(b));
}

__global__ __launch_bounds__(256, 2) void flash_kernel(const bf16* __restrict__ q,
                                                       const bf16* __restrict__ k,
                                                       const bf16* __restrict__ vt,
                                                       bf16* __restrict__ opart,
                                                       float* __restrict__ lpart) {
  __shared__ bf16 Ks[2][64 * 128];  // [k-row 64][h 128], byte^=((r&7)<<4) swizzle
  __shared__ bf16 Vs[2][128 * 64];  // [h 128][t 64],     byte^=((h&7)<<4) swizzle

  const int b = blockIdx.x & 7;
  int j = (NSLAB - 1) - (blockIdx.x >> 3);  // heavy (high-qb) blocks first
  int qb = 0, ns = 1;
  while (j >= ns) { j -= ns; ++qb; ns = ((2 * qb + 1) >> 2) + 1; }
  const int s = j;
  const int kt0 = s * 4;
  const int kt1 = min(kt0 + 3, 2 * qb + 1);

  const int tid = threadIdx.x;
  const int lane = tid & 63;
  const int wave = tid >> 6;
  const int l32 = lane & 31;
  const int hi = lane >> 5;
  const int qrow = qb * 128 + wave * 32 + l32;
  const int kdiag = qb * 4 + wave;  // diagonal 32-block for this wave

  // Q fragments: lane holds q-row = l&31 (B-operand of swapped QK^T)
  bf16x8 qf[8];
  {
    const bf16* qp = q + (size_t)(b * TT + qrow) * HH + hi * 8;
#pragma unroll
    for (int h16 = 0; h16 < 8; ++h16) qf[h16] = *(const bf16x8*)(qp + h16 * 16);
  }

  f32x16 O[4];
#pragma unroll
  for (int ht = 0; ht < 4; ++ht)
#pragma unroll
    for (int r = 0; r < 16; ++r) O[ht][r] = 0.f;
  float L = 0.f;

  // staging source mapping (pre-swizzled so linear LDS + swizzled read match)
  const int krow_s = tid >> 4;                    // K: row within 16-row round
  const int kchk_s = (tid & 15) ^ (krow_s & 7);   // 16B chunk, inverse-swizzled
  const int vrow_s = tid >> 3;                    // V: row within 32-row round
  const int vchk_s = (tid & 7) ^ (vrow_s & 7);
  const bf16* kg = k + (size_t)b * TT * HH;
  const bf16* vg = vt + (size_t)b * HH * TT;

  auto stageKV = [&](int bufi, int kt) {
#pragma unroll
    for (int i = 0; i < 4; ++i)
      gload_lds16(kg + (size_t)(kt * 64 + i * 16 + krow_s) * HH + kchk_s * 8,
                  &Ks[bufi][(i * 256 + wave * 64) * 8]);
#pragma unroll
    for (int i = 0; i < 4; ++i)
      gload_lds16(vg + (size_t)(i * 32 + vrow_s) * TT + kt * 64 + vchk_s * 8,
                  &Vs[bufi][(i * 256 + wave * 64) * 8]);
  };

  const int kxor = (l32 & 7) << 3;        // read-side XOR, element units
  const float c_ = 0.12753257680406733f;  // log2(e)/sqrt(128)

  stageKV(0, kt0);
  __syncthreads();  // prologue drain: buf0 staged

  int buf = 0;
  for (int kt = kt0; kt <= kt1; ++kt) {
    if (kt < kt1) stageKV(buf ^ 1, kt + 1);  // issue next tile early

#pragma unroll
    for (int khalf = 0; khalf < 2; ++khalf) {
      const int k32 = kt * 2 + khalf;
      if (k32 <= kdiag) {
        // K fragments from LDS (swizzled read)
        const bf16* kls = &Ks[buf][(khalf * 32 + l32) * 128];
        bf16x8 kf[8];
#pragma unroll
        for (int h16 = 0; h16 < 8; ++h16)
          kf[h16] = *(const bf16x8*)&kls[(h16 * 16 + hi * 8) ^ kxor];

        // S^T[k][q] = K . Q^T  (lane: q=l&31; regs: k=(r&3)+8*(r>>2)+4*hi)
        f32x16 S;
#pragma unroll
        for (int r = 0; r < 16; ++r) S[r] = 0.f;
        __builtin_amdgcn_s_setprio(1);
#pragma unroll
        for (int h16 = 0; h16 < 8; ++h16)
          S = __builtin_amdgcn_mfma_f32_32x32x16_bf16(kf[h16], qf[h16], S, 0, 0, 0);
        __builtin_amdgcn_s_setprio(0);

        // softmax (no-max; scale folded into exp2), in registers
        float p[16];
        if (k32 == kdiag) {
          const int kkb = k32 * 32 + 4 * hi;
#pragma unroll
          for (int r = 0; r < 16; ++r) {
            int kk = kkb + (r & 3) + 8 * (r >> 2);
            float pv = (kk <= qrow) ? exp2f(S[r] * c_) : 0.f;
            p[r] = pv;
            L += pv;
          }
        } else {
#pragma unroll
          for (int r = 0; r < 16; ++r) {
            float pv = exp2f(S[r] * c_);
            p[r] = pv;
            L += pv;
          }
        }

        // P -> bf16 A-frag (pack + permlane32_swap, T12), then PV from LDS V
#pragma unroll
        for (int s16 = 0; s16 < 2; ++s16) {
          unsigned w0 = pk2(p[s16 * 8 + 0], p[s16 * 8 + 1]);
          unsigned w1 = pk2(p[s16 * 8 + 2], p[s16 * 8 + 3]);
          unsigned w2 = pk2(p[s16 * 8 + 4], p[s16 * 8 + 5]);
          unsigned w3 = pk2(p[s16 * 8 + 6], p[s16 * 8 + 7]);
          plswap(w0, w2);
          plswap(w1, w3);
          union { unsigned u[4]; bf16x8 v; } af;
          af.u[0] = w0;
          af.u[1] = w1;
          af.u[2] = w2;
          af.u[3] = w3;
          bf16x8 vf[4];
#pragma unroll
          for (int ht = 0; ht < 4; ++ht)
            vf[ht] = *(const bf16x8*)&Vs[buf][(l32 + 32 * ht) * 64 +
                                             ((khalf * 32 + s16 * 16 + hi * 8) ^ kxor)];
          __builtin_amdgcn_s_setprio(1);
#pragma unroll
          for (int ht = 0; ht < 4; ++ht)
            O[ht] = __builtin_amdgcn_mfma_f32_32x32x16_bf16(af.v, vf[ht], O[ht], 0, 0, 0);
          __builtin_amdgcn_s_setprio(0);
        }
      }
    }
    __syncthreads();  // drains vmcnt(0) after compute; readers done before restage
    buf ^= 1;
  }

  L += __shfl_xor(L, 32, 64);  // partner half holds complementary k-subset

  const size_t slab = (size_t)(b * NSLAB + qb_off(qb) + s);
  bf16* op = opart + slab * (128 * 128) + (size_t)wave * 32 * 128;
#pragma unroll
  for (int ht = 0; ht < 4; ++ht)
#pragma unroll
    for (int r = 0; r < 16; ++r) {
      int qr = (r & 3) + 8 * (r >> 2) + 4 * hi;
      op[qr * 128 + ht * 32 + l32] = (bf16)O[ht][r];
    }
  if (hi == 0) lpart[slab * 128 + wave * 32 + l32] = L;
}

// ---- combine: grid (b, qt16, half) -> 2048 blocks of 128 thr ----
__global__ __launch_bounds__(128) void combine_kernel(const bf16* __restrict__ opart,
                                                      const float* __restrict__ lpart,
                                                      float* __restrict__ out) {
  const int b = blockIdx.x;
  const int qt16 = blockIdx.y;
  const int half = blockIdx.z;
  const int row = threadIdx.x >> 3;
  const int colo = (threadIdx.x & 7) * 8 + half * 64;
  const int qb = qt16 >> 3;
  const int srow = (qt16 & 7) * 16 + row;
  const int ns = ((2 * qb + 1) >> 2) + 1;  // 1..8
  const size_t slab0 = (size_t)(b * NSLAB + qb_off(qb));

  float acc[8];
#pragma unroll
  for (int j = 0; j < 8; ++j) acc[j] = 0.f;
  float L = 0.f;

  int s = 0;
  for (; s + 4 <= ns; s += 4) {
    float l0 = lpart[(slab0 + s + 0) * 128 + srow];
    float l1 = lpart[(slab0 + s + 1) * 128 + srow];
    float l2 = lpart[(slab0 + s + 2) * 128 + srow];
    float l3 = lpart[(slab0 + s + 3) * 128 + srow];
    bf16x8 v0 = *(const bf16x8*)(opart + (slab0 + s + 0) * (128 * 128) + srow * 128 + colo);
    bf16x8 v1 = *(const bf16x8*)(opart + (slab0 + s + 1) * (128 * 128) + srow * 128 + colo);
    bf16x8 v2 = *(const bf16x8*)(opart + (slab0 + s + 2) * (128 * 128) + srow * 128 + colo);
    bf16x8 v3 = *(const bf16x8*)(opart + (slab0 + s + 3) * (128 * 128) + srow * 128 + colo);
    L += (l0 + l1) + (l2 + l3);
#pragma unroll
    for (int j = 0; j < 8; ++j)
      acc[j] += ((float)v0[j] + (float)v1[j]) + ((float)v2[j] + (float)v3[j]);
  }
  for (; s < ns; ++s) {
    L += lpart[(slab0 + s) * 128 + srow];
    bf16x8 ov = *(const bf16x8*)(opart + (slab0 + s) * (128 * 128) + srow * 128 + colo);
#pragma unroll
    for (int j = 0; j < 8; ++j) acc[j] += (float)ov[j];
  }
  float invL = 1.f / L;
  float* o = out + ((size_t)(b * TT + qt16 * 16 + row)) * HH + colo;
  f32x4 o0, o1;
#pragma unroll
  for (int j = 0; j < 4; ++j) { o0[j] = acc[j] * invL; o1[j] = acc[j + 4] * invL; }
  *(f32x4*)o = o0;
  *(f32x4*)(o + 4) = o1;
}

extern "C" void kernel_launch(void* const* d_in, const int* in_sizes, int n_in,
                              void* d_out, int out_size, void* d_ws, size_t ws_size,
                              hipStream_t stream) {
  const float* x = (const float*)d_in[0];
  const float* wq = (const float*)d_in[1];
  const float* wk = (const float*)d_in[2];
  const float* wv = (const float*)d_in[3];
  float* out = (float*)d_out;

  char* ws = (char*)d_ws;
  const size_t NE = (size_t)BB * TT * HH;  // 2,097,152
  bf16* wt = (bf16*)ws;                    // 768 KB
  bf16* xb = (bf16*)(ws + (1 << 20));      // 32 MiB (16384x1024 bf16)
  bf16* q = (bf16*)(ws + (33 << 20));      // 4 MiB each
  bf16* k = q + NE;
  bf16* vt = k + NE;                       // V written pre-transposed by gemm
  // xb is dead after gemm; opart/lpart alias its region (19.2 MB < 32 MiB)
  bf16* opart = xb;
  float* lpart = (float*)(opart + (size_t)(BB * NSLAB) * 128 * 128);
  // total ws use: 45 MiB

  prep_kernel<<<dim3(4192), 256, 0, stream>>>(x, xb, wq, wk, wv, wt);
  gemm_kernel<<<dim3(128, 4), 256, 0, stream>>>(xb, wt, q, k, vt);
  flash_kernel<<<dim3(576), 256, 0, stream>>>(q, k, vt, opart, lpart);
  combine_kernel<<<dim3(8, 128, 2), 128, 0, stream>>>(opart, lpart, out);
}